// Round 10
// baseline (217.959 us; speedup 1.0000x reference)
//
#include <hip/hip_runtime.h>

#define N_NODES 100000
#define N_EDGES 1600000
#define NBINS   100000
#define LN_EPS  1e-5f

#define NG 8                 // range groups
#define NS 32                // edge slices
#define RANGE 12500          // NBINS / NG
#define SLICE_I4 12500       // (N_EDGES/4) / NS

#define XB_BLOCKS   256

typedef unsigned int u32;
typedef unsigned short u16;
typedef __attribute__((ext_vector_type(8))) short short8;
typedef __attribute__((ext_vector_type(4))) float f32x4;

__device__ __forceinline__ u16 f2bf(float f) {
    u32 u = __float_as_uint(f);
    u32 r = (u + 0x7FFFu + ((u >> 16) & 1u)) >> 16;   // round-to-nearest-even
    return (u16)r;
}
__device__ __forceinline__ float bf_lo(u32 u) { return __uint_as_float(u << 16); }
__device__ __forceinline__ float bf_hi(u32 u) { return __uint_as_float(u & 0xFFFF0000u); }

// ---------------------------------------------------------------------------
// Fused prep (no atomics): block 0 = Wf fragment table; [1,XB] = xb bf16 cast.
// ---------------------------------------------------------------------------
__global__ __launch_bounds__(256) void k_prep(
    const float* __restrict__ x, const float* __restrict__ bases,
    const float* __restrict__ loopw,
    u16* __restrict__ wf, u16* __restrict__ xb)
{
    const int t = threadIdx.x;
    if (blockIdx.x == 0) {
        for (int idx = t; idx < 4 * 10 * 64 * 8; idx += 256) {
            const int j = idx & 7;
            const int l = (idx >> 3) & 63;
            const int rest = idx >> 9;
            const int ks = rest % 10;
            const int ct = rest / 10;
            const int k = ks * 32 + (l >> 4) * 8 + j;
            const int c = ct * 16 + (l & 15);
            float v;
            if (k < 256) v = bases[(k & 3) * 4096 + (k >> 2) * 64 + c];
            else         v = loopw[(k - 256) * 64 + c];
            wf[idx] = f2bf(v);
        }
    } else {
        const int bb = blockIdx.x - 1;
        for (int i = bb * 256 + t; i < N_NODES * 16; i += XB_BLOCKS * 256) {
            const float4 v = ((const float4*)x)[i];
            uint2 w;
            w.x = (u32)f2bf(v.x) | ((u32)f2bf(v.y) << 16);
            w.y = (u32)f2bf(v.z) | ((u32)f2bf(v.w) << 16);
            ((uint2*)xb)[i] = w;
        }
    }
}

// ---------------------------------------------------------------------------
// LDS-privatized histogram. Mapping s=blockIdx&31, g=blockIdx>>5 puts all 8
// range-groups of slice s on the SAME XCD (round-robin bid%8) -> slice dst
// stream fetched once into that L2, not 8x from HBM.
// ---------------------------------------------------------------------------
__global__ __launch_bounds__(256) void k_hist(
    const int* __restrict__ dst, u32* __restrict__ priv)
{
    __shared__ u32 lh[RANGE];
    const int t = threadIdx.x;
    for (int j = t; j < RANGE; j += 256) lh[j] = 0u;
    __syncthreads();
    const int s = blockIdx.x & (NS - 1);
    const int g = blockIdx.x >> 5;
    const int lo = g * RANGE;
    const int4* dst4 = (const int4*)dst;
    const int i0 = s * SLICE_I4;
    for (int i = i0 + t; i < i0 + SLICE_I4; i += 256) {
        const int4 d4 = dst4[i];
#pragma unroll
        for (int q = 0; q < 4; ++q) {
            const int d = (q == 0) ? d4.x : (q == 1) ? d4.y
                        : (q == 2) ? d4.z : d4.w;
            const u32 rel = (u32)(d - lo);
            if (rel < (u32)RANGE) atomicAdd(&lh[rel], 1u);
        }
    }
    __syncthreads();
    u32* pb = priv + (size_t)(g * NS + s) * RANGE;
    for (int j = t; j < RANGE; j += 256) pb[j] = lh[j];
}

// ---------------------------------------------------------------------------
// Scan: per bin, sum the 32 private slices -> counts; block-exclusive scan ->
// offs (block-local); write back per-slice running prefixes into priv.
// ---------------------------------------------------------------------------
__global__ __launch_bounds__(1024) void k_scan_block(
    u32* __restrict__ priv, u32* __restrict__ counts,
    u32* __restrict__ offs, u32* __restrict__ bsums)
{
    __shared__ u32 wsum[16];
    const int t = threadIdx.x;
    const int lane = t & 63, wid = t >> 6;
    const int idx = blockIdx.x * 1024 + t;
    u32 sv[NS];
    u32 v = 0u;
    u32 g = 0, local = 0;
    if (idx < NBINS) {
        g = (u32)idx / (u32)RANGE;
        local = (u32)idx - g * (u32)RANGE;
#pragma unroll
        for (int s = 0; s < NS; ++s) {
            sv[s] = priv[(size_t)(g * NS + s) * RANGE + local];
            v += sv[s];
        }
    }
    u32 sc = v;
#pragma unroll
    for (int off = 1; off < 64; off <<= 1) {
        u32 u = __shfl_up(sc, off, 64);
        if (lane >= off) sc += u;
    }
    if (lane == 63) wsum[wid] = sc;
    __syncthreads();
    if (wid == 0) {
        u32 w = (lane < 16) ? wsum[lane] : 0u;
#pragma unroll
        for (int off = 1; off < 16; off <<= 1) {
            u32 u = __shfl_up(w, off, 64);
            if (lane >= off) w += u;
        }
        if (lane < 16) wsum[lane] = w;
    }
    __syncthreads();
    const u32 prefix = (wid > 0) ? wsum[wid - 1] : 0u;
    const u32 incl = sc + prefix;
    const u32 excl = incl - v;
    if (idx < NBINS) {
        offs[idx] = excl;
        counts[idx] = v;
        u32 run = excl;
#pragma unroll
        for (int s = 0; s < NS; ++s) {
            priv[(size_t)(g * NS + s) * RANGE + local] = run;
            run += sv[s];
        }
    }
    if (t == 1023) bsums[blockIdx.x] = incl;
}

__global__ __launch_bounds__(128) void k_scan_sums(
    const u32* __restrict__ bsums, u32* __restrict__ boffs, int nb)
{
    __shared__ u32 s[128];
    const int t = threadIdx.x;
    u32 v = (t < nb) ? bsums[t] : 0u;
    s[t] = v;
    __syncthreads();
#pragma unroll
    for (int off = 1; off < 128; off <<= 1) {
        u32 xv = (t >= off) ? s[t - off] : 0u;
        __syncthreads();
        s[t] += xv;
        __syncthreads();
    }
    boffs[t] = s[t] - v;
}

// ---------------------------------------------------------------------------
// Scatter with LDS cursors, XCD-co-located slices (same mapping as k_hist).
// Reads src/et directly (slice fetched once per XCD), packs inline.
// No global atomics; priv/boffs read-only.
// ---------------------------------------------------------------------------
__global__ __launch_bounds__(256) void k_scatter(
    const int* __restrict__ dst, const int* __restrict__ src,
    const int* __restrict__ et,
    const u32* __restrict__ priv, const u32* __restrict__ boffs,
    u32* __restrict__ packed)
{
    __shared__ u32 cur[RANGE];
    const int t = threadIdx.x;
    const int s = blockIdx.x & (NS - 1);
    const int g = blockIdx.x >> 5;
    const int lo = g * RANGE;
    const u32* pb = priv + (size_t)(g * NS + s) * RANGE;
    for (int j = t; j < RANGE; j += 256)
        cur[j] = pb[j] + boffs[(lo + j) >> 10];
    __syncthreads();
    const int4* dst4 = (const int4*)dst;
    const int4* src4 = (const int4*)src;
    const int4* et4  = (const int4*)et;
    const int i0 = s * SLICE_I4;
    for (int i = i0 + t; i < i0 + SLICE_I4; i += 256) {
        const int4 d4 = dst4[i];
        const int4 s4 = src4[i];
        const int4 e4 = et4[i];
#pragma unroll
        for (int q = 0; q < 4; ++q) {
            const int d = (q == 0) ? d4.x : (q == 1) ? d4.y
                        : (q == 2) ? d4.z : d4.w;
            const int sn = (q == 0) ? s4.x : (q == 1) ? s4.y
                         : (q == 2) ? s4.z : s4.w;
            const int ev = (q == 0) ? e4.x : (q == 1) ? e4.y
                         : (q == 2) ? e4.z : e4.w;
            const u32 rel = (u32)(d - lo);
            if (rel < (u32)RANGE) {
                const u32 pos = atomicAdd(&cur[rel], 1u);
                packed[pos] = (u32)sn | ((u32)ev << 20);
            }
        }
    }
}

// ---------------------------------------------------------------------------
// Input-space aggregation, PAIR-gather: lane = u32 feature-pair (2 bf16);
// lanes 0-31 process even edges, 32-63 odd edges -> one load covers 2 edges.
// comp broadcast from LDS (ds_read_b128). Final shfl_xor(32) merge; lanes<32
// store 16B. Segment = [offs[n]+boffs, +counts[n]); offs never mutated.
// ---------------------------------------------------------------------------
__global__ __launch_bounds__(256) void k_agg(
    const u32* __restrict__ xb32,       // [N][32] u32
    const float4* __restrict__ comp,
    const u32* __restrict__ packed,
    const u32* __restrict__ offs, const u32* __restrict__ boffs,
    const u32* __restrict__ counts,
    uint4* __restrict__ y)              // [N][32] uint4 rows... (32 per row)
{
    __shared__ float4 lcomp[16];
    const int t = threadIdx.x;
    if (t < 16) lcomp[t] = comp[t];
    __syncthreads();

    const int lane = t & 63;
    const int wid = t >> 6;
    const int half = lane >> 5;         // 0 = even edge, 1 = odd edge
    const int fl = lane & 31;           // feature-pair index
    const int waves = gridDim.x * 4;

    for (int n0 = blockIdx.x * 4 + wid; n0 < N_NODES; n0 += waves) {
        const int n = __builtin_amdgcn_readfirstlane(n0);
        const u32 deg = counts[n];
        const u32 base = offs[n] + boffs[n >> 10];
        f32x4 acc0 = {0.f, 0.f, 0.f, 0.f};   // feature 2*fl, bases 0..3
        f32x4 acc1 = {0.f, 0.f, 0.f, 0.f};   // feature 2*fl+1
        u32 done = 0;
        while (done < deg) {
            u32 cnt = deg - done;
            if (cnt > 64u) cnt = 64u;
            const u32 li = ((u32)lane < cnt) ? (u32)lane : 0u;
            const u32 recs = packed[base + done + li];
            u32 k = 0;
            for (; k + 16 <= cnt; k += 16) {      // 8 pairs, no masking
                u32 rr[16];
#pragma unroll
                for (int q = 0; q < 16; ++q)
                    rr[q] = (u32)__builtin_amdgcn_readlane((int)recs, (int)(k + q));
                u32 rsel[8], hv[8];
#pragma unroll
                for (int p = 0; p < 8; ++p) {
                    rsel[p] = half ? rr[2 * p + 1] : rr[2 * p];
                    hv[p] = xb32[(size_t)(rsel[p] & 0xFFFFFu) * 32 + fl];
                }
#pragma unroll
                for (int p = 0; p < 8; ++p) {
                    const float4 c = lcomp[rsel[p] >> 20];
                    const float x0 = bf_lo(hv[p]), x1 = bf_hi(hv[p]);
                    acc0.x = fmaf(c.x, x0, acc0.x);
                    acc0.y = fmaf(c.y, x0, acc0.y);
                    acc0.z = fmaf(c.z, x0, acc0.z);
                    acc0.w = fmaf(c.w, x0, acc0.w);
                    acc1.x = fmaf(c.x, x1, acc1.x);
                    acc1.y = fmaf(c.y, x1, acc1.y);
                    acc1.z = fmaf(c.z, x1, acc1.z);
                    acc1.w = fmaf(c.w, x1, acc1.w);
                }
            }
            for (; k < cnt; k += 2) {             // masked pair tail
                const u32 rA = (u32)__builtin_amdgcn_readlane((int)recs, (int)k);
                const u32 kb = (k + 1 < 64u) ? k + 1 : k;
                const u32 rB = (u32)__builtin_amdgcn_readlane((int)recs, (int)kb);
                const bool hasB = (k + 1) < cnt;
                const u32 rsel = (half && hasB) ? rB : rA;
                const u32 hv = xb32[(size_t)(rsel & 0xFFFFFu) * 32 + fl];
                const float4 c = lcomp[rsel >> 20];
                float x0 = bf_lo(hv), x1 = bf_hi(hv);
                if (half && !hasB) { x0 = 0.f; x1 = 0.f; }
                acc0.x = fmaf(c.x, x0, acc0.x);
                acc0.y = fmaf(c.y, x0, acc0.y);
                acc0.z = fmaf(c.z, x0, acc0.z);
                acc0.w = fmaf(c.w, x0, acc0.w);
                acc1.x = fmaf(c.x, x1, acc1.x);
                acc1.y = fmaf(c.y, x1, acc1.y);
                acc1.z = fmaf(c.z, x1, acc1.z);
                acc1.w = fmaf(c.w, x1, acc1.w);
            }
            done += cnt;
        }
        // merge halves
#pragma unroll
        for (int b = 0; b < 4; ++b) {
            acc0[b] += __shfl_xor(acc0[b], 32, 64);
            acc1[b] += __shfl_xor(acc1[b], 32, 64);
        }
        if (lane < 32) {
            uint4 w;
            w.x = (u32)f2bf(acc0.x) | ((u32)f2bf(acc0.y) << 16);
            w.y = (u32)f2bf(acc0.z) | ((u32)f2bf(acc0.w) << 16);
            w.z = (u32)f2bf(acc1.x) | ((u32)f2bf(acc1.y) << 16);
            w.w = (u32)f2bf(acc1.z) | ((u32)f2bf(acc1.w) << 16);
            y[(size_t)n * 32 + fl] = w;
        }
    }
}

// ---------------------------------------------------------------------------
// Fused GEMM + epilogue: [N,320]bf16 (y||xb) @ Wf[320,64]bf16, then
// +bias, LeakyReLU, LayerNorm (16-lane-group shfl reductions), write out.
// ---------------------------------------------------------------------------
__global__ __launch_bounds__(256) void k_gemm_ln(
    const short8* __restrict__ yf,   // [N*32]
    const short8* __restrict__ xbf,  // [N*8]
    const short8* __restrict__ wf,   // [4][10][64]
    const float* __restrict__ bias, const float* __restrict__ gamma,
    const float* __restrict__ beta, float* __restrict__ out)
{
    const int lane = threadIdx.x & 63;
    const int wid = threadIdx.x >> 6;
    const int m = lane & 15, kg = lane >> 4;
    float bsv[4], gm[4], bt[4];
#pragma unroll
    for (int ct = 0; ct < 4; ++ct) {
        bsv[ct] = bias[ct * 16 + m];
        gm[ct] = gamma[ct * 16 + m];
        bt[ct] = beta[ct * 16 + m];
    }
    const int ntiles = N_NODES / 16;              // 6250 exact
    for (int tile = blockIdx.x * 4 + wid; tile < ntiles; tile += gridDim.x * 4) {
        const int base = tile * 16;
        const int row = base + m;
        short8 a[10];
#pragma unroll
        for (int ks = 0; ks < 8; ++ks)
            a[ks] = yf[(size_t)row * 32 + ks * 4 + kg];
        a[8] = xbf[(size_t)row * 8 + kg];
        a[9] = xbf[(size_t)row * 8 + 4 + kg];
        f32x4 acc[4];
#pragma unroll
        for (int ct = 0; ct < 4; ++ct) {
            acc[ct] = (f32x4){0.f, 0.f, 0.f, 0.f};
#pragma unroll
            for (int ks = 0; ks < 10; ++ks)
                acc[ct] = __builtin_amdgcn_mfma_f32_16x16x32_bf16(
                    a[ks], wf[(ct * 10 + ks) * 64 + lane], acc[ct], 0, 0, 0);
        }
        float v[4][4];
#pragma unroll
        for (int ct = 0; ct < 4; ++ct)
#pragma unroll
            for (int r = 0; r < 4; ++r) {
                const float u = acc[ct][r] + bsv[ct];
                v[ct][r] = (u >= 0.f) ? u : 0.1f * u;
            }
#pragma unroll
        for (int r = 0; r < 4; ++r) {
            float s1 = v[0][r] + v[1][r] + v[2][r] + v[3][r];
#pragma unroll
            for (int mk = 1; mk < 16; mk <<= 1) s1 += __shfl_xor(s1, mk, 64);
            const float mu = s1 * (1.f / 64.f);
            float s2 = 0.f;
#pragma unroll
            for (int ct = 0; ct < 4; ++ct) {
                const float d = v[ct][r] - mu;
                s2 += d * d;
            }
#pragma unroll
            for (int mk = 1; mk < 16; mk <<= 1) s2 += __shfl_xor(s2, mk, 64);
            const float rstd = rsqrtf(s2 * (1.f / 64.f) + LN_EPS);
            const int ro = base + kg * 4 + r;
#pragma unroll
            for (int ct = 0; ct < 4; ++ct)
                out[(size_t)ro * 64 + ct * 16 + m] =
                    (v[ct][r] - mu) * rstd * gm[ct] + bt[ct];
        }
    }
}

// ---------------------------------------------------------------------------
// Fallback (tiny ws): direct per-edge compute with atomics + separate finalize.
// ---------------------------------------------------------------------------
__global__ __launch_bounds__(256) void k_edge_direct(
    const float* __restrict__ x, const float* __restrict__ bases,
    const float* __restrict__ comp,
    const int* __restrict__ src, const int* __restrict__ dst,
    const int* __restrict__ et, float* __restrict__ agg)
{
    const int lane = threadIdx.x & 63;
    int e = blockIdx.x * 4 + (threadIdx.x >> 6);
    if (e >= N_EDGES) return;
    e = __builtin_amdgcn_readfirstlane(e);
    const int s = src[e], d = dst[e], r = et[e];
    const float4 c = *(const float4*)(comp + r * 4);
    const float* xr = x + (size_t)s * 64;
    float acc = 0.f;
    for (int i = 0; i < 64; ++i) {
        const float w = c.x * bases[i * 64 + lane]
                      + c.y * bases[4096 + i * 64 + lane]
                      + c.z * bases[8192 + i * 64 + lane]
                      + c.w * bases[12288 + i * 64 + lane];
        acc = fmaf(xr[i], w, acc);
    }
    atomicAdd(&agg[(size_t)d * 64 + lane], acc);
}

__global__ __launch_bounds__(256) void k_finalize(
    const float* __restrict__ x, const float* __restrict__ loopw,
    const float* __restrict__ bias, const float* __restrict__ gamma,
    const float* __restrict__ beta, float* __restrict__ out)
{
    const int t = threadIdx.x;
    const int lane = t & 63;
    const int wid = t >> 6;
    float wreg[64];
#pragma unroll
    for (int i = 0; i < 64; ++i)
        wreg[i] = loopw[i * 64 + lane];
    const float bs = bias[lane], gm = gamma[lane], bt = beta[lane];
    const int waves = gridDim.x * 4;
    for (int n = blockIdx.x * 4 + wid; n < N_NODES; n += waves) {
        float xv = x[(size_t)n * 64 + lane];
        const int xbv = __float_as_int(xv);
        float slv = bs;
#pragma unroll
        for (int i = 0; i < 64; ++i) {
            const float s = __int_as_float(__builtin_amdgcn_readlane(xbv, i));
            slv = fmaf(s, wreg[i], slv);
        }
        float v = out[(size_t)n * 64 + lane] + slv;
        v = (v >= 0.f) ? v : 0.1f * v;
        float s1 = v;
#pragma unroll
        for (int mm = 32; mm >= 1; mm >>= 1) s1 += __shfl_xor(s1, mm, 64);
        const float mu = s1 * (1.f / 64.f);
        const float dv = v - mu;
        float s2 = dv * dv;
#pragma unroll
        for (int mm = 32; mm >= 1; mm >>= 1) s2 += __shfl_xor(s2, mm, 64);
        const float var = s2 * (1.f / 64.f);
        out[(size_t)n * 64 + lane] = dv * rsqrtf(var + LN_EPS) * gm + bt;
    }
}

// ---------------------------------------------------------------------------
extern "C" void kernel_launch(void* const* d_in, const int* in_sizes, int n_in,
                              void* d_out, int out_size, void* d_ws, size_t ws_size,
                              hipStream_t stream) {
    const float* x     = (const float*)d_in[0];
    const float* bases = (const float*)d_in[1];
    const float* comp  = (const float*)d_in[2];
    const float* loopw = (const float*)d_in[3];
    const float* bias  = (const float*)d_in[4];
    const float* gamma = (const float*)d_in[5];
    const float* beta  = (const float*)d_in[6];
    const int*   src   = (const int*)d_in[7];
    const int*   dst   = (const int*)d_in[8];
    const int*   et    = (const int*)d_in[9];
    float* out = (float*)d_out;

    size_t p = 0;
    auto alloc = [&](size_t bytes) {
        size_t cur = p;
        p = (p + bytes + 255) & ~(size_t)255;
        return cur;
    };
    char* ws = (char*)d_ws;
    const size_t o_counts = alloc((size_t)NBINS * sizeof(u32));            // 0.4 MB
    const size_t o_wf     = alloc((size_t)4 * 10 * 64 * 8 * sizeof(u16));  // 40 KB
    const size_t o_xb     = alloc((size_t)N_NODES * 64 * sizeof(u16));     // 12.8 MB
    const size_t o_y      = alloc((size_t)N_NODES * 256 * sizeof(u16));    // 51.2 MB
    const size_t o_priv   = alloc((size_t)NG * NS * RANGE * sizeof(u32));  // 12.8 MB
    const size_t o_offs   = alloc((size_t)NBINS * sizeof(u32));
    const size_t o_bsums  = alloc(128 * sizeof(u32));
    const size_t o_boffs  = alloc(128 * sizeof(u32));
    const size_t o_packed = alloc((size_t)N_EDGES * sizeof(u32));          // 6.4 MB
    const size_t need = p;

    if (ws_size >= need) {
        u32* counts = (u32*)(ws + o_counts);
        u16* wfp    = (u16*)(ws + o_wf);
        u16* xb     = (u16*)(ws + o_xb);
        u16* y      = (u16*)(ws + o_y);
        u32* priv   = (u32*)(ws + o_priv);
        u32* offs   = (u32*)(ws + o_offs);
        u32* bsums  = (u32*)(ws + o_bsums);
        u32* boffs  = (u32*)(ws + o_boffs);
        u32* packed = (u32*)(ws + o_packed);

        k_prep<<<1 + XB_BLOCKS, 256, 0, stream>>>(x, bases, loopw, wfp, xb);
        k_hist<<<NG * NS, 256, 0, stream>>>(dst, priv);
        const int scan_blocks = (NBINS + 1023) / 1024;  // 98
        k_scan_block<<<scan_blocks, 1024, 0, stream>>>(priv, counts, offs, bsums);
        k_scan_sums<<<1, 128, 0, stream>>>(bsums, boffs, scan_blocks);
        k_scatter<<<NG * NS, 256, 0, stream>>>(dst, src, et, priv, boffs, packed);
        k_agg<<<2048, 256, 0, stream>>>((const u32*)xb, (const float4*)comp,
                                        packed, offs, boffs, counts, (uint4*)y);
        k_gemm_ln<<<(N_NODES / 16 + 3) / 4, 256, 0, stream>>>(
            (const short8*)y, (const short8*)xb, (const short8*)wfp,
            bias, gamma, beta, out);
    } else {
        hipMemsetAsync(d_out, 0, (size_t)N_NODES * 64 * sizeof(float), stream);
        k_edge_direct<<<(N_EDGES + 3) / 4, 256, 0, stream>>>(
            x, bases, comp, src, dst, et, out);
        k_finalize<<<2048, 256, 0, stream>>>(x, loopw, bias, gamma, beta, out);
    }
}

// Round 11
// 157.331 us; speedup vs baseline: 1.3853x; 1.3853x over previous
//
#include <hip/hip_runtime.h>

#define N_NODES 100000
#define N_EDGES 1600000
#define NBINS   100000
#define LN_EPS  1e-5f

#define NG 8                 // range groups
#define NS 32                // edge slices
#define RANGE 12500          // NBINS / NG
#define SLICE_I4 12500       // (N_EDGES/4) / NS
#define SCAN_BLOCKS 98       // ceil(NBINS/1024)

#define XB_BLOCKS   256

typedef unsigned int u32;
typedef unsigned short u16;
typedef __attribute__((ext_vector_type(8))) short short8;
typedef __attribute__((ext_vector_type(4))) float f32x4;

__device__ __forceinline__ u16 f2bf(float f) {
    u32 u = __float_as_uint(f);
    u32 r = (u + 0x7FFFu + ((u >> 16) & 1u)) >> 16;   // round-to-nearest-even
    return (u16)r;
}
__device__ __forceinline__ float bf2f(u16 h) {
    return __uint_as_float((u32)h << 16);
}

// ---------------------------------------------------------------------------
// Fused prep + histogram, one launch (independent work):
//   blocks [0, 256):        LDS-privatized hist; s=blockIdx&31, g=blockIdx>>5
//                           puts all 8 range-groups of slice s on ONE XCD ->
//                           slice stream fetched once into that L2.
//   block  256:             Wf fragment table (40 KB)
//   blocks [257, 257+256):  xb[n][i] = bf16(x[n][i])
// ---------------------------------------------------------------------------
__global__ __launch_bounds__(256) void k_prep_hist(
    const float* __restrict__ x, const float* __restrict__ bases,
    const float* __restrict__ loopw, const int* __restrict__ dst,
    u16* __restrict__ wf, u16* __restrict__ xb, u32* __restrict__ priv)
{
    __shared__ u32 lh[RANGE];
    const int t = threadIdx.x;
    if (blockIdx.x < NG * NS) {
        for (int j = t; j < RANGE; j += 256) lh[j] = 0u;
        __syncthreads();
        const int s = blockIdx.x & (NS - 1);
        const int g = blockIdx.x >> 5;
        const int lo = g * RANGE;
        const int4* dst4 = (const int4*)dst;
        const int i0 = s * SLICE_I4;
        for (int i = i0 + t; i < i0 + SLICE_I4; i += 256) {
            const int4 d4 = dst4[i];
#pragma unroll
            for (int q = 0; q < 4; ++q) {
                const int d = (q == 0) ? d4.x : (q == 1) ? d4.y
                            : (q == 2) ? d4.z : d4.w;
                const u32 rel = (u32)(d - lo);
                if (rel < (u32)RANGE) atomicAdd(&lh[rel], 1u);
            }
        }
        __syncthreads();
        u32* pb = priv + (size_t)(g * NS + s) * RANGE;
        for (int j = t; j < RANGE; j += 256) pb[j] = lh[j];
    } else if (blockIdx.x == NG * NS) {
        for (int idx = t; idx < 4 * 10 * 64 * 8; idx += 256) {
            const int j = idx & 7;
            const int l = (idx >> 3) & 63;
            const int rest = idx >> 9;
            const int ks = rest % 10;
            const int ct = rest / 10;
            const int k = ks * 32 + (l >> 4) * 8 + j;
            const int c = ct * 16 + (l & 15);
            float v;
            if (k < 256) v = bases[(k & 3) * 4096 + (k >> 2) * 64 + c];
            else         v = loopw[(k - 256) * 64 + c];
            wf[idx] = f2bf(v);
        }
    } else {
        const int bb = blockIdx.x - NG * NS - 1;
        for (int i = bb * 256 + t; i < N_NODES * 16; i += XB_BLOCKS * 256) {
            const float4 v = ((const float4*)x)[i];
            uint2 w;
            w.x = (u32)f2bf(v.x) | ((u32)f2bf(v.y) << 16);
            w.y = (u32)f2bf(v.z) | ((u32)f2bf(v.w) << 16);
            ((uint2*)xb)[i] = w;
        }
    }
}

// ---------------------------------------------------------------------------
// Scan: per bin, sum the 32 private slices -> counts; block-exclusive scan ->
// offs (block-local); write back per-slice running prefixes into priv.
// Block totals -> bsums (prefixed inline by consumers).
// ---------------------------------------------------------------------------
__global__ __launch_bounds__(1024) void k_scan_block(
    u32* __restrict__ priv, u32* __restrict__ counts,
    u32* __restrict__ offs, u32* __restrict__ bsums)
{
    __shared__ u32 wsum[16];
    const int t = threadIdx.x;
    const int lane = t & 63, wid = t >> 6;
    const int idx = blockIdx.x * 1024 + t;
    u32 sv[NS];
    u32 v = 0u;
    u32 g = 0, local = 0;
    if (idx < NBINS) {
        g = (u32)idx / (u32)RANGE;
        local = (u32)idx - g * (u32)RANGE;
#pragma unroll
        for (int s = 0; s < NS; ++s) {
            sv[s] = priv[(size_t)(g * NS + s) * RANGE + local];
            v += sv[s];
        }
    }
    u32 sc = v;
#pragma unroll
    for (int off = 1; off < 64; off <<= 1) {
        u32 u = __shfl_up(sc, off, 64);
        if (lane >= off) sc += u;
    }
    if (lane == 63) wsum[wid] = sc;
    __syncthreads();
    if (wid == 0) {
        u32 w = (lane < 16) ? wsum[lane] : 0u;
#pragma unroll
        for (int off = 1; off < 16; off <<= 1) {
            u32 u = __shfl_up(w, off, 64);
            if (lane >= off) w += u;
        }
        if (lane < 16) wsum[lane] = w;
    }
    __syncthreads();
    const u32 prefix = (wid > 0) ? wsum[wid - 1] : 0u;
    const u32 incl = sc + prefix;
    const u32 excl = incl - v;
    if (idx < NBINS) {
        offs[idx] = excl;
        counts[idx] = v;
        u32 run = excl;
#pragma unroll
        for (int s = 0; s < NS; ++s) {
            priv[(size_t)(g * NS + s) * RANGE + local] = run;
            run += sv[s];
        }
    }
    if (t == 1023) bsums[blockIdx.x] = incl;
}

// ---------------------------------------------------------------------------
// Scatter with LDS cursors, XCD-co-located slices. Wave 0 computes the
// 98-entry bsums exclusive prefix inline (replaces k_scan_sums launch);
// block 0 publishes it as boffs for k_agg. Reads src/et directly, packs
// inline. No global atomics; priv read-only.
// ---------------------------------------------------------------------------
__global__ __launch_bounds__(256) void k_scatter(
    const int* __restrict__ dst, const int* __restrict__ src,
    const int* __restrict__ et,
    const u32* __restrict__ priv, const u32* __restrict__ bsums,
    u32* __restrict__ boffs, u32* __restrict__ packed)
{
    __shared__ u32 cur[RANGE];
    __shared__ u32 sb[128];
    const int t = threadIdx.x;
    if (t < 64) {
        const u32 a = (t < SCAN_BLOCKS) ? bsums[t] : 0u;
        u32 s1 = a;
#pragma unroll
        for (int off = 1; off < 64; off <<= 1) {
            u32 u = __shfl_up(s1, off, 64);
            if (t >= off) s1 += u;
        }
        sb[t] = s1 - a;                               // exclusive, first 64
        const u32 tot0 = __shfl(s1, 63, 64);
        const int t2 = t + 64;
        const u32 b = (t2 < SCAN_BLOCKS) ? bsums[t2] : 0u;
        u32 s2 = b;
#pragma unroll
        for (int off = 1; off < 64; off <<= 1) {
            u32 u = __shfl_up(s2, off, 64);
            if (t >= off) s2 += u;
        }
        sb[t2] = tot0 + s2 - b;                       // exclusive, rest
    }
    __syncthreads();

    const int s = blockIdx.x & (NS - 1);
    const int g = blockIdx.x >> 5;
    const int lo = g * RANGE;
    if (blockIdx.x == 0) {                            // publish boffs for k_agg
        if (t < 128) boffs[t] = sb[t];
    }
    const u32* pb = priv + (size_t)(g * NS + s) * RANGE;
    for (int j = t; j < RANGE; j += 256)
        cur[j] = pb[j] + sb[(lo + j) >> 10];
    __syncthreads();
    const int4* dst4 = (const int4*)dst;
    const int4* src4 = (const int4*)src;
    const int4* et4  = (const int4*)et;
    const int i0 = s * SLICE_I4;
    for (int i = i0 + t; i < i0 + SLICE_I4; i += 256) {
        const int4 d4 = dst4[i];
        const int4 s4 = src4[i];
        const int4 e4 = et4[i];
#pragma unroll
        for (int q = 0; q < 4; ++q) {
            const int d = (q == 0) ? d4.x : (q == 1) ? d4.y
                        : (q == 2) ? d4.z : d4.w;
            const int sn = (q == 0) ? s4.x : (q == 1) ? s4.y
                         : (q == 2) ? s4.z : s4.w;
            const int ev = (q == 0) ? e4.x : (q == 1) ? e4.y
                         : (q == 2) ? e4.z : e4.w;
            const u32 rel = (u32)(d - lo);
            if (rel < (u32)RANGE) {
                const u32 pos = atomicAdd(&cur[rel], 1u);
                packed[pos] = (u32)sn | ((u32)ev << 20);
            }
        }
    }
}

// ---------------------------------------------------------------------------
// Input-space aggregation (R9-proven fast path): one wave per dst node,
// lane = input feature i. Records batch-loaded coalesced, broadcast via
// v_readlane (SGPR -> comp[] becomes scalar loads); u16 gather per lane
// (coalesced 128B/edge); 8-deep unroll for MLP. No LDS, VGPR ~12.
// ---------------------------------------------------------------------------
__global__ __launch_bounds__(256) void k_agg(
    const u16* __restrict__ xb, const float4* __restrict__ comp,
    const u32* __restrict__ packed,
    const u32* __restrict__ offs, const u32* __restrict__ boffs,
    const u32* __restrict__ counts,
    uint2* __restrict__ y)           // [N*64] uint2 (= [N][256] bf16)
{
    const int t = threadIdx.x;
    const int lane = t & 63;
    const int wid = t >> 6;
    const int waves = gridDim.x * 4;
    const u16* xbl = xb + lane;

    for (int n0 = blockIdx.x * 4 + wid; n0 < N_NODES; n0 += waves) {
        const int n = __builtin_amdgcn_readfirstlane(n0);
        const u32 deg = counts[n];
        const u32 base = offs[n] + boffs[n >> 10];
        float a0 = 0.f, a1 = 0.f, a2 = 0.f, a3 = 0.f;
        u32 done = 0;
        while (done < deg) {
            u32 cnt = deg - done;
            if (cnt > 64u) cnt = 64u;
            const u32 li = ((u32)lane < cnt) ? (u32)lane : 0u;
            const u32 recs = packed[base + done + li];
            u32 k = 0;
            for (; k + 8 <= cnt; k += 8) {
                u32 rr[8];
#pragma unroll
                for (int q = 0; q < 8; ++q)
                    rr[q] = (u32)__builtin_amdgcn_readlane((int)recs, (int)(k + q));
                u16 hv[8];
#pragma unroll
                for (int q = 0; q < 8; ++q)
                    hv[q] = xbl[(size_t)(rr[q] & 0xFFFFFu) * 64];
                float4 cc[8];
#pragma unroll
                for (int q = 0; q < 8; ++q) cc[q] = comp[rr[q] >> 20];
#pragma unroll
                for (int q = 0; q < 8; ++q) {
                    const float xf = bf2f(hv[q]);
                    a0 = fmaf(cc[q].x, xf, a0);
                    a1 = fmaf(cc[q].y, xf, a1);
                    a2 = fmaf(cc[q].z, xf, a2);
                    a3 = fmaf(cc[q].w, xf, a3);
                }
            }
            for (; k < cnt; ++k) {
                const u32 r0 = (u32)__builtin_amdgcn_readlane((int)recs, (int)k);
                const float4 c0 = comp[r0 >> 20];
                const float xf = bf2f(xbl[(size_t)(r0 & 0xFFFFFu) * 64]);
                a0 = fmaf(c0.x, xf, a0);
                a1 = fmaf(c0.y, xf, a1);
                a2 = fmaf(c0.z, xf, a2);
                a3 = fmaf(c0.w, xf, a3);
            }
            done += cnt;
        }
        uint2 w;
        w.x = (u32)f2bf(a0) | ((u32)f2bf(a1) << 16);
        w.y = (u32)f2bf(a2) | ((u32)f2bf(a3) << 16);
        y[(size_t)n * 64 + lane] = w;
    }
}

// ---------------------------------------------------------------------------
// Fused GEMM + epilogue: [N,320]bf16 (y||xb) @ Wf[320,64]bf16, then
// +bias, LeakyReLU, LayerNorm (16-lane-group shfl reductions), write out.
// ---------------------------------------------------------------------------
__global__ __launch_bounds__(256) void k_gemm_ln(
    const short8* __restrict__ yf,   // [N*32]
    const short8* __restrict__ xbf,  // [N*8]
    const short8* __restrict__ wf,   // [4][10][64]
    const float* __restrict__ bias, const float* __restrict__ gamma,
    const float* __restrict__ beta, float* __restrict__ out)
{
    const int lane = threadIdx.x & 63;
    const int wid = threadIdx.x >> 6;
    const int m = lane & 15, kg = lane >> 4;
    float bsv[4], gm[4], bt[4];
#pragma unroll
    for (int ct = 0; ct < 4; ++ct) {
        bsv[ct] = bias[ct * 16 + m];
        gm[ct] = gamma[ct * 16 + m];
        bt[ct] = beta[ct * 16 + m];
    }
    const int ntiles = N_NODES / 16;              // 6250 exact
    for (int tile = blockIdx.x * 4 + wid; tile < ntiles; tile += gridDim.x * 4) {
        const int base = tile * 16;
        const int row = base + m;
        short8 a[10];
#pragma unroll
        for (int ks = 0; ks < 8; ++ks)
            a[ks] = yf[(size_t)row * 32 + ks * 4 + kg];
        a[8] = xbf[(size_t)row * 8 + kg];
        a[9] = xbf[(size_t)row * 8 + 4 + kg];
        f32x4 acc[4];
#pragma unroll
        for (int ct = 0; ct < 4; ++ct) {
            acc[ct] = (f32x4){0.f, 0.f, 0.f, 0.f};
#pragma unroll
            for (int ks = 0; ks < 10; ++ks)
                acc[ct] = __builtin_amdgcn_mfma_f32_16x16x32_bf16(
                    a[ks], wf[(ct * 10 + ks) * 64 + lane], acc[ct], 0, 0, 0);
        }
        float v[4][4];
#pragma unroll
        for (int ct = 0; ct < 4; ++ct)
#pragma unroll
            for (int r = 0; r < 4; ++r) {
                const float u = acc[ct][r] + bsv[ct];
                v[ct][r] = (u >= 0.f) ? u : 0.1f * u;
            }
#pragma unroll
        for (int r = 0; r < 4; ++r) {
            float s1 = v[0][r] + v[1][r] + v[2][r] + v[3][r];
#pragma unroll
            for (int mk = 1; mk < 16; mk <<= 1) s1 += __shfl_xor(s1, mk, 64);
            const float mu = s1 * (1.f / 64.f);
            float s2 = 0.f;
#pragma unroll
            for (int ct = 0; ct < 4; ++ct) {
                const float d = v[ct][r] - mu;
                s2 += d * d;
            }
#pragma unroll
            for (int mk = 1; mk < 16; mk <<= 1) s2 += __shfl_xor(s2, mk, 64);
            const float rstd = rsqrtf(s2 * (1.f / 64.f) + LN_EPS);
            const int ro = base + kg * 4 + r;
#pragma unroll
            for (int ct = 0; ct < 4; ++ct)
                out[(size_t)ro * 64 + ct * 16 + m] =
                    (v[ct][r] - mu) * rstd * gm[ct] + bt[ct];
        }
    }
}

// ---------------------------------------------------------------------------
// Fallback (tiny ws): direct per-edge compute with atomics + separate finalize.
// ---------------------------------------------------------------------------
__global__ __launch_bounds__(256) void k_edge_direct(
    const float* __restrict__ x, const float* __restrict__ bases,
    const float* __restrict__ comp,
    const int* __restrict__ src, const int* __restrict__ dst,
    const int* __restrict__ et, float* __restrict__ agg)
{
    const int lane = threadIdx.x & 63;
    int e = blockIdx.x * 4 + (threadIdx.x >> 6);
    if (e >= N_EDGES) return;
    e = __builtin_amdgcn_readfirstlane(e);
    const int s = src[e], d = dst[e], r = et[e];
    const float4 c = *(const float4*)(comp + r * 4);
    const float* xr = x + (size_t)s * 64;
    float acc = 0.f;
    for (int i = 0; i < 64; ++i) {
        const float w = c.x * bases[i * 64 + lane]
                      + c.y * bases[4096 + i * 64 + lane]
                      + c.z * bases[8192 + i * 64 + lane]
                      + c.w * bases[12288 + i * 64 + lane];
        acc = fmaf(xr[i], w, acc);
    }
    atomicAdd(&agg[(size_t)d * 64 + lane], acc);
}

__global__ __launch_bounds__(256) void k_finalize(
    const float* __restrict__ x, const float* __restrict__ loopw,
    const float* __restrict__ bias, const float* __restrict__ gamma,
    const float* __restrict__ beta, float* __restrict__ out)
{
    const int t = threadIdx.x;
    const int lane = t & 63;
    const int wid = t >> 6;
    float wreg[64];
#pragma unroll
    for (int i = 0; i < 64; ++i)
        wreg[i] = loopw[i * 64 + lane];
    const float bs = bias[lane], gm = gamma[lane], bt = beta[lane];
    const int waves = gridDim.x * 4;
    for (int n = blockIdx.x * 4 + wid; n < N_NODES; n += waves) {
        float xv = x[(size_t)n * 64 + lane];
        const int xbv = __float_as_int(xv);
        float slv = bs;
#pragma unroll
        for (int i = 0; i < 64; ++i) {
            const float s = __int_as_float(__builtin_amdgcn_readlane(xbv, i));
            slv = fmaf(s, wreg[i], slv);
        }
        float v = out[(size_t)n * 64 + lane] + slv;
        v = (v >= 0.f) ? v : 0.1f * v;
        float s1 = v;
#pragma unroll
        for (int mm = 32; mm >= 1; mm >>= 1) s1 += __shfl_xor(s1, mm, 64);
        const float mu = s1 * (1.f / 64.f);
        const float dv = v - mu;
        float s2 = dv * dv;
#pragma unroll
        for (int mm = 32; mm >= 1; mm >>= 1) s2 += __shfl_xor(s2, mm, 64);
        const float var = s2 * (1.f / 64.f);
        out[(size_t)n * 64 + lane] = dv * rsqrtf(var + LN_EPS) * gm + bt;
    }
}

// ---------------------------------------------------------------------------
extern "C" void kernel_launch(void* const* d_in, const int* in_sizes, int n_in,
                              void* d_out, int out_size, void* d_ws, size_t ws_size,
                              hipStream_t stream) {
    const float* x     = (const float*)d_in[0];
    const float* bases = (const float*)d_in[1];
    const float* comp  = (const float*)d_in[2];
    const float* loopw = (const float*)d_in[3];
    const float* bias  = (const float*)d_in[4];
    const float* gamma = (const float*)d_in[5];
    const float* beta  = (const float*)d_in[6];
    const int*   src   = (const int*)d_in[7];
    const int*   dst   = (const int*)d_in[8];
    const int*   et    = (const int*)d_in[9];
    float* out = (float*)d_out;

    size_t p = 0;
    auto alloc = [&](size_t bytes) {
        size_t cur = p;
        p = (p + bytes + 255) & ~(size_t)255;
        return cur;
    };
    char* ws = (char*)d_ws;
    const size_t o_counts = alloc((size_t)NBINS * sizeof(u32));            // 0.4 MB
    const size_t o_wf     = alloc((size_t)4 * 10 * 64 * 8 * sizeof(u16));  // 40 KB
    const size_t o_xb     = alloc((size_t)N_NODES * 64 * sizeof(u16));     // 12.8 MB
    const size_t o_y      = alloc((size_t)N_NODES * 256 * sizeof(u16));    // 51.2 MB
    const size_t o_priv   = alloc((size_t)NG * NS * RANGE * sizeof(u32));  // 12.8 MB
    const size_t o_offs   = alloc((size_t)NBINS * sizeof(u32));
    const size_t o_bsums  = alloc(128 * sizeof(u32));
    const size_t o_boffs  = alloc(128 * sizeof(u32));
    const size_t o_packed = alloc((size_t)N_EDGES * sizeof(u32));          // 6.4 MB
    const size_t need = p;

    if (ws_size >= need) {
        u32* counts = (u32*)(ws + o_counts);
        u16* wfp    = (u16*)(ws + o_wf);
        u16* xb     = (u16*)(ws + o_xb);
        u16* y      = (u16*)(ws + o_y);
        u32* priv   = (u32*)(ws + o_priv);
        u32* offs   = (u32*)(ws + o_offs);
        u32* bsums  = (u32*)(ws + o_bsums);
        u32* boffs  = (u32*)(ws + o_boffs);
        u32* packed = (u32*)(ws + o_packed);

        k_prep_hist<<<NG * NS + 1 + XB_BLOCKS, 256, 0, stream>>>(
            x, bases, loopw, dst, wfp, xb, priv);
        k_scan_block<<<SCAN_BLOCKS, 1024, 0, stream>>>(priv, counts, offs, bsums);
        k_scatter<<<NG * NS, 256, 0, stream>>>(dst, src, et, priv, bsums,
                                               boffs, packed);
        k_agg<<<2048, 256, 0, stream>>>(xb, (const float4*)comp, packed,
                                        offs, boffs, counts, (uint2*)y);
        k_gemm_ln<<<(N_NODES / 16 + 3) / 4, 256, 0, stream>>>(
            (const short8*)y, (const short8*)xb, (const short8*)wfp,
            bias, gamma, beta, out);
    } else {
        hipMemsetAsync(d_out, 0, (size_t)N_NODES * 64 * sizeof(float), stream);
        k_edge_direct<<<(N_EDGES + 3) / 4, 256, 0, stream>>>(
            x, bases, comp, src, dst, et, out);
        k_finalize<<<2048, 256, 0, stream>>>(x, loopw, bias, gamma, beta, out);
    }
}

// Round 12
// 129.866 us; speedup vs baseline: 1.6783x; 1.2115x over previous
//
#include <hip/hip_runtime.h>

#define N_NODES 100000
#define N_EDGES 1600000
#define NBINS   100000
#define LN_EPS  1e-5f

#define NG 8                 // range groups
#define NS 32                // edge slices
#define RANGE 12500          // NBINS / NG
#define SLICE_I4 12500       // (N_EDGES/4) / NS
#define SCAN_BLOCKS 98       // ceil(NBINS/1024)

#define XB_BLOCKS   64       // 1024-thread blocks

typedef unsigned int u32;
typedef unsigned short u16;
typedef __attribute__((ext_vector_type(8))) short short8;
typedef __attribute__((ext_vector_type(4))) float f32x4;

__device__ __forceinline__ u16 f2bf(float f) {
    u32 u = __float_as_uint(f);
    u32 r = (u + 0x7FFFu + ((u >> 16) & 1u)) >> 16;   // round-to-nearest-even
    return (u16)r;
}
__device__ __forceinline__ float bf2f(u16 h) {
    return __uint_as_float((u32)h << 16);
}

// ---------------------------------------------------------------------------
// Fused prep + histogram, one launch, 1024-thread blocks (16 waves/block for
// latency hiding):
//   blocks [0, 256):        LDS-privatized hist; s=blockIdx&31, g=blockIdx>>5
//                           co-locates all groups of slice s on one XCD.
//   block  256:             Wf fragment table (40 KB)
//   blocks [257, 257+64):   xb[n][i] = bf16(x[n][i])
// ---------------------------------------------------------------------------
__global__ __launch_bounds__(1024) void k_prep_hist(
    const float* __restrict__ x, const float* __restrict__ bases,
    const float* __restrict__ loopw, const int* __restrict__ dst,
    u16* __restrict__ wf, u16* __restrict__ xb, u32* __restrict__ priv)
{
    __shared__ u32 lh[RANGE];
    const int t = threadIdx.x;
    if (blockIdx.x < NG * NS) {
        for (int j = t; j < RANGE; j += 1024) lh[j] = 0u;
        __syncthreads();
        const int s = blockIdx.x & (NS - 1);
        const int g = blockIdx.x >> 5;
        const int lo = g * RANGE;
        const int4* dst4 = (const int4*)dst;
        const int i0 = s * SLICE_I4;
        for (int i = i0 + t; i < i0 + SLICE_I4; i += 1024) {
            const int4 d4 = dst4[i];
#pragma unroll
            for (int q = 0; q < 4; ++q) {
                const int d = (q == 0) ? d4.x : (q == 1) ? d4.y
                            : (q == 2) ? d4.z : d4.w;
                const u32 rel = (u32)(d - lo);
                if (rel < (u32)RANGE) atomicAdd(&lh[rel], 1u);
            }
        }
        __syncthreads();
        u32* pb = priv + (size_t)(g * NS + s) * RANGE;
        for (int j = t; j < RANGE; j += 1024) pb[j] = lh[j];
    } else if (blockIdx.x == NG * NS) {
        for (int idx = t; idx < 4 * 10 * 64 * 8; idx += 1024) {
            const int j = idx & 7;
            const int l = (idx >> 3) & 63;
            const int rest = idx >> 9;
            const int ks = rest % 10;
            const int ct = rest / 10;
            const int k = ks * 32 + (l >> 4) * 8 + j;
            const int c = ct * 16 + (l & 15);
            float v;
            if (k < 256) v = bases[(k & 3) * 4096 + (k >> 2) * 64 + c];
            else         v = loopw[(k - 256) * 64 + c];
            wf[idx] = f2bf(v);
        }
    } else {
        const int bb = blockIdx.x - NG * NS - 1;
        for (int i = bb * 1024 + t; i < N_NODES * 16; i += XB_BLOCKS * 1024) {
            const float4 v = ((const float4*)x)[i];
            uint2 w;
            w.x = (u32)f2bf(v.x) | ((u32)f2bf(v.y) << 16);
            w.y = (u32)f2bf(v.z) | ((u32)f2bf(v.w) << 16);
            ((uint2*)xb)[i] = w;
        }
    }
}

// ---------------------------------------------------------------------------
// Scan: per bin, sum the 32 private slices -> counts; block-exclusive scan ->
// offs (block-local); write back per-slice running prefixes into priv.
// ---------------------------------------------------------------------------
__global__ __launch_bounds__(1024) void k_scan_block(
    u32* __restrict__ priv, u32* __restrict__ counts,
    u32* __restrict__ offs, u32* __restrict__ bsums)
{
    __shared__ u32 wsum[16];
    const int t = threadIdx.x;
    const int lane = t & 63, wid = t >> 6;
    const int idx = blockIdx.x * 1024 + t;
    u32 sv[NS];
    u32 v = 0u;
    u32 g = 0, local = 0;
    if (idx < NBINS) {
        g = (u32)idx / (u32)RANGE;
        local = (u32)idx - g * (u32)RANGE;
#pragma unroll
        for (int s = 0; s < NS; ++s) {
            sv[s] = priv[(size_t)(g * NS + s) * RANGE + local];
            v += sv[s];
        }
    }
    u32 sc = v;
#pragma unroll
    for (int off = 1; off < 64; off <<= 1) {
        u32 u = __shfl_up(sc, off, 64);
        if (lane >= off) sc += u;
    }
    if (lane == 63) wsum[wid] = sc;
    __syncthreads();
    if (wid == 0) {
        u32 w = (lane < 16) ? wsum[lane] : 0u;
#pragma unroll
        for (int off = 1; off < 16; off <<= 1) {
            u32 u = __shfl_up(w, off, 64);
            if (lane >= off) w += u;
        }
        if (lane < 16) wsum[lane] = w;
    }
    __syncthreads();
    const u32 prefix = (wid > 0) ? wsum[wid - 1] : 0u;
    const u32 incl = sc + prefix;
    const u32 excl = incl - v;
    if (idx < NBINS) {
        offs[idx] = excl;
        counts[idx] = v;
        u32 run = excl;
#pragma unroll
        for (int s = 0; s < NS; ++s) {
            priv[(size_t)(g * NS + s) * RANGE + local] = run;
            run += sv[s];
        }
    }
    if (t == 1023) bsums[blockIdx.x] = incl;
}

// ---------------------------------------------------------------------------
// Scatter with LDS cursors, 1024-thread blocks, XCD-co-located slices.
// First wave computes the 98-entry bsums exclusive prefix inline; block 0
// publishes it as boffs for k_agg. No global atomics; priv read-only.
// ---------------------------------------------------------------------------
__global__ __launch_bounds__(1024) void k_scatter(
    const int* __restrict__ dst, const int* __restrict__ src,
    const int* __restrict__ et,
    const u32* __restrict__ priv, const u32* __restrict__ bsums,
    u32* __restrict__ boffs, u32* __restrict__ packed)
{
    __shared__ u32 cur[RANGE];
    __shared__ u32 sb[128];
    const int t = threadIdx.x;
    if (t < 64) {
        const u32 a = (t < SCAN_BLOCKS) ? bsums[t] : 0u;
        u32 s1 = a;
#pragma unroll
        for (int off = 1; off < 64; off <<= 1) {
            u32 u = __shfl_up(s1, off, 64);
            if (t >= off) s1 += u;
        }
        sb[t] = s1 - a;                               // exclusive, first 64
        const u32 tot0 = __shfl(s1, 63, 64);
        const int t2 = t + 64;
        const u32 b = (t2 < SCAN_BLOCKS) ? bsums[t2] : 0u;
        u32 s2 = b;
#pragma unroll
        for (int off = 1; off < 64; off <<= 1) {
            u32 u = __shfl_up(s2, off, 64);
            if (t >= off) s2 += u;
        }
        sb[t2] = tot0 + s2 - b;                       // exclusive, rest
    }
    __syncthreads();

    const int s = blockIdx.x & (NS - 1);
    const int g = blockIdx.x >> 5;
    const int lo = g * RANGE;
    if (blockIdx.x == 0) {                            // publish boffs for k_agg
        if (t < 128) boffs[t] = sb[t];
    }
    const u32* pb = priv + (size_t)(g * NS + s) * RANGE;
    for (int j = t; j < RANGE; j += 1024)
        cur[j] = pb[j] + sb[(lo + j) >> 10];
    __syncthreads();
    const int4* dst4 = (const int4*)dst;
    const int4* src4 = (const int4*)src;
    const int4* et4  = (const int4*)et;
    const int i0 = s * SLICE_I4;
    for (int i = i0 + t; i < i0 + SLICE_I4; i += 1024) {
        const int4 d4 = dst4[i];
        const int4 s4 = src4[i];
        const int4 e4 = et4[i];
#pragma unroll
        for (int q = 0; q < 4; ++q) {
            const int d = (q == 0) ? d4.x : (q == 1) ? d4.y
                        : (q == 2) ? d4.z : d4.w;
            const int sn = (q == 0) ? s4.x : (q == 1) ? s4.y
                         : (q == 2) ? s4.z : s4.w;
            const int ev = (q == 0) ? e4.x : (q == 1) ? e4.y
                         : (q == 2) ? e4.z : e4.w;
            const u32 rel = (u32)(d - lo);
            if (rel < (u32)RANGE) {
                const u32 pos = atomicAdd(&cur[rel], 1u);
                packed[pos] = (u32)sn | ((u32)ev << 20);
            }
        }
    }
}

// ---------------------------------------------------------------------------
// Input-space aggregation (R9-proven fast path): one wave per dst node,
// lane = input feature i. Records batch-loaded coalesced, broadcast via
// v_readlane (SGPR -> comp[] becomes scalar loads); u16 gather per lane
// (coalesced 128B/edge); 8-deep unroll for MLP. No LDS, VGPR ~12.
// ---------------------------------------------------------------------------
__global__ __launch_bounds__(256) void k_agg(
    const u16* __restrict__ xb, const float4* __restrict__ comp,
    const u32* __restrict__ packed,
    const u32* __restrict__ offs, const u32* __restrict__ boffs,
    const u32* __restrict__ counts,
    uint2* __restrict__ y)           // [N*64] uint2 (= [N][256] bf16)
{
    const int t = threadIdx.x;
    const int lane = t & 63;
    const int wid = t >> 6;
    const int waves = gridDim.x * 4;
    const u16* xbl = xb + lane;

    for (int n0 = blockIdx.x * 4 + wid; n0 < N_NODES; n0 += waves) {
        const int n = __builtin_amdgcn_readfirstlane(n0);
        const u32 deg = counts[n];
        const u32 base = offs[n] + boffs[n >> 10];
        float a0 = 0.f, a1 = 0.f, a2 = 0.f, a3 = 0.f;
        u32 done = 0;
        while (done < deg) {
            u32 cnt = deg - done;
            if (cnt > 64u) cnt = 64u;
            const u32 li = ((u32)lane < cnt) ? (u32)lane : 0u;
            const u32 recs = packed[base + done + li];
            u32 k = 0;
            for (; k + 8 <= cnt; k += 8) {
                u32 rr[8];
#pragma unroll
                for (int q = 0; q < 8; ++q)
                    rr[q] = (u32)__builtin_amdgcn_readlane((int)recs, (int)(k + q));
                u16 hv[8];
#pragma unroll
                for (int q = 0; q < 8; ++q)
                    hv[q] = xbl[(size_t)(rr[q] & 0xFFFFFu) * 64];
                float4 cc[8];
#pragma unroll
                for (int q = 0; q < 8; ++q) cc[q] = comp[rr[q] >> 20];
#pragma unroll
                for (int q = 0; q < 8; ++q) {
                    const float xf = bf2f(hv[q]);
                    a0 = fmaf(cc[q].x, xf, a0);
                    a1 = fmaf(cc[q].y, xf, a1);
                    a2 = fmaf(cc[q].z, xf, a2);
                    a3 = fmaf(cc[q].w, xf, a3);
                }
            }
            for (; k < cnt; ++k) {
                const u32 r0 = (u32)__builtin_amdgcn_readlane((int)recs, (int)k);
                const float4 c0 = comp[r0 >> 20];
                const float xf = bf2f(xbl[(size_t)(r0 & 0xFFFFFu) * 64]);
                a0 = fmaf(c0.x, xf, a0);
                a1 = fmaf(c0.y, xf, a1);
                a2 = fmaf(c0.z, xf, a2);
                a3 = fmaf(c0.w, xf, a3);
            }
            done += cnt;
        }
        uint2 w;
        w.x = (u32)f2bf(a0) | ((u32)f2bf(a1) << 16);
        w.y = (u32)f2bf(a2) | ((u32)f2bf(a3) << 16);
        y[(size_t)n * 64 + lane] = w;
    }
}

// ---------------------------------------------------------------------------
// Fused GEMM + epilogue: [N,320]bf16 (y||xb) @ Wf[320,64]bf16, then
// +bias, LeakyReLU, LayerNorm (16-lane-group shfl reductions), write out.
// ---------------------------------------------------------------------------
__global__ __launch_bounds__(256) void k_gemm_ln(
    const short8* __restrict__ yf,   // [N*32]
    const short8* __restrict__ xbf,  // [N*8]
    const short8* __restrict__ wf,   // [4][10][64]
    const float* __restrict__ bias, const float* __restrict__ gamma,
    const float* __restrict__ beta, float* __restrict__ out)
{
    const int lane = threadIdx.x & 63;
    const int wid = threadIdx.x >> 6;
    const int m = lane & 15, kg = lane >> 4;
    float bsv[4], gm[4], bt[4];
#pragma unroll
    for (int ct = 0; ct < 4; ++ct) {
        bsv[ct] = bias[ct * 16 + m];
        gm[ct] = gamma[ct * 16 + m];
        bt[ct] = beta[ct * 16 + m];
    }
    const int ntiles = N_NODES / 16;              // 6250 exact
    for (int tile = blockIdx.x * 4 + wid; tile < ntiles; tile += gridDim.x * 4) {
        const int base = tile * 16;
        const int row = base + m;
        short8 a[10];
#pragma unroll
        for (int ks = 0; ks < 8; ++ks)
            a[ks] = yf[(size_t)row * 32 + ks * 4 + kg];
        a[8] = xbf[(size_t)row * 8 + kg];
        a[9] = xbf[(size_t)row * 8 + 4 + kg];
        f32x4 acc[4];
#pragma unroll
        for (int ct = 0; ct < 4; ++ct) {
            acc[ct] = (f32x4){0.f, 0.f, 0.f, 0.f};
#pragma unroll
            for (int ks = 0; ks < 10; ++ks)
                acc[ct] = __builtin_amdgcn_mfma_f32_16x16x32_bf16(
                    a[ks], wf[(ct * 10 + ks) * 64 + lane], acc[ct], 0, 0, 0);
        }
        float v[4][4];
#pragma unroll
        for (int ct = 0; ct < 4; ++ct)
#pragma unroll
            for (int r = 0; r < 4; ++r) {
                const float u = acc[ct][r] + bsv[ct];
                v[ct][r] = (u >= 0.f) ? u : 0.1f * u;
            }
#pragma unroll
        for (int r = 0; r < 4; ++r) {
            float s1 = v[0][r] + v[1][r] + v[2][r] + v[3][r];
#pragma unroll
            for (int mk = 1; mk < 16; mk <<= 1) s1 += __shfl_xor(s1, mk, 64);
            const float mu = s1 * (1.f / 64.f);
            float s2 = 0.f;
#pragma unroll
            for (int ct = 0; ct < 4; ++ct) {
                const float d = v[ct][r] - mu;
                s2 += d * d;
            }
#pragma unroll
            for (int mk = 1; mk < 16; mk <<= 1) s2 += __shfl_xor(s2, mk, 64);
            const float rstd = rsqrtf(s2 * (1.f / 64.f) + LN_EPS);
            const int ro = base + kg * 4 + r;
#pragma unroll
            for (int ct = 0; ct < 4; ++ct)
                out[(size_t)ro * 64 + ct * 16 + m] =
                    (v[ct][r] - mu) * rstd * gm[ct] + bt[ct];
        }
    }
}

// ---------------------------------------------------------------------------
// Fallback (tiny ws): direct per-edge compute with atomics + separate finalize.
// ---------------------------------------------------------------------------
__global__ __launch_bounds__(256) void k_edge_direct(
    const float* __restrict__ x, const float* __restrict__ bases,
    const float* __restrict__ comp,
    const int* __restrict__ src, const int* __restrict__ dst,
    const int* __restrict__ et, float* __restrict__ agg)
{
    const int lane = threadIdx.x & 63;
    int e = blockIdx.x * 4 + (threadIdx.x >> 6);
    if (e >= N_EDGES) return;
    e = __builtin_amdgcn_readfirstlane(e);
    const int s = src[e], d = dst[e], r = et[e];
    const float4 c = *(const float4*)(comp + r * 4);
    const float* xr = x + (size_t)s * 64;
    float acc = 0.f;
    for (int i = 0; i < 64; ++i) {
        const float w = c.x * bases[i * 64 + lane]
                      + c.y * bases[4096 + i * 64 + lane]
                      + c.z * bases[8192 + i * 64 + lane]
                      + c.w * bases[12288 + i * 64 + lane];
        acc = fmaf(xr[i], w, acc);
    }
    atomicAdd(&agg[(size_t)d * 64 + lane], acc);
}

__global__ __launch_bounds__(256) void k_finalize(
    const float* __restrict__ x, const float* __restrict__ loopw,
    const float* __restrict__ bias, const float* __restrict__ gamma,
    const float* __restrict__ beta, float* __restrict__ out)
{
    const int t = threadIdx.x;
    const int lane = t & 63;
    const int wid = t >> 6;
    float wreg[64];
#pragma unroll
    for (int i = 0; i < 64; ++i)
        wreg[i] = loopw[i * 64 + lane];
    const float bs = bias[lane], gm = gamma[lane], bt = beta[lane];
    const int waves = gridDim.x * 4;
    for (int n = blockIdx.x * 4 + wid; n < N_NODES; n += waves) {
        float xv = x[(size_t)n * 64 + lane];
        const int xbv = __float_as_int(xv);
        float slv = bs;
#pragma unroll
        for (int i = 0; i < 64; ++i) {
            const float s = __int_as_float(__builtin_amdgcn_readlane(xbv, i));
            slv = fmaf(s, wreg[i], slv);
        }
        float v = out[(size_t)n * 64 + lane] + slv;
        v = (v >= 0.f) ? v : 0.1f * v;
        float s1 = v;
#pragma unroll
        for (int mm = 32; mm >= 1; mm >>= 1) s1 += __shfl_xor(s1, mm, 64);
        const float mu = s1 * (1.f / 64.f);
        const float dv = v - mu;
        float s2 = dv * dv;
#pragma unroll
        for (int mm = 32; mm >= 1; mm >>= 1) s2 += __shfl_xor(s2, mm, 64);
        const float var = s2 * (1.f / 64.f);
        out[(size_t)n * 64 + lane] = dv * rsqrtf(var + LN_EPS) * gm + bt;
    }
}

// ---------------------------------------------------------------------------
extern "C" void kernel_launch(void* const* d_in, const int* in_sizes, int n_in,
                              void* d_out, int out_size, void* d_ws, size_t ws_size,
                              hipStream_t stream) {
    const float* x     = (const float*)d_in[0];
    const float* bases = (const float*)d_in[1];
    const float* comp  = (const float*)d_in[2];
    const float* loopw = (const float*)d_in[3];
    const float* bias  = (const float*)d_in[4];
    const float* gamma = (const float*)d_in[5];
    const float* beta  = (const float*)d_in[6];
    const int*   src   = (const int*)d_in[7];
    const int*   dst   = (const int*)d_in[8];
    const int*   et    = (const int*)d_in[9];
    float* out = (float*)d_out;

    size_t p = 0;
    auto alloc = [&](size_t bytes) {
        size_t cur = p;
        p = (p + bytes + 255) & ~(size_t)255;
        return cur;
    };
    char* ws = (char*)d_ws;
    const size_t o_counts = alloc((size_t)NBINS * sizeof(u32));            // 0.4 MB
    const size_t o_wf     = alloc((size_t)4 * 10 * 64 * 8 * sizeof(u16));  // 40 KB
    const size_t o_xb     = alloc((size_t)N_NODES * 64 * sizeof(u16));     // 12.8 MB
    const size_t o_y      = alloc((size_t)N_NODES * 256 * sizeof(u16));    // 51.2 MB
    const size_t o_priv   = alloc((size_t)NG * NS * RANGE * sizeof(u32));  // 12.8 MB
    const size_t o_offs   = alloc((size_t)NBINS * sizeof(u32));
    const size_t o_bsums  = alloc(128 * sizeof(u32));
    const size_t o_boffs  = alloc(128 * sizeof(u32));
    const size_t o_packed = alloc((size_t)N_EDGES * sizeof(u32));          // 6.4 MB
    const size_t need = p;

    if (ws_size >= need) {
        u32* counts = (u32*)(ws + o_counts);
        u16* wfp    = (u16*)(ws + o_wf);
        u16* xb     = (u16*)(ws + o_xb);
        u16* y      = (u16*)(ws + o_y);
        u32* priv   = (u32*)(ws + o_priv);
        u32* offs   = (u32*)(ws + o_offs);
        u32* bsums  = (u32*)(ws + o_bsums);
        u32* boffs  = (u32*)(ws + o_boffs);
        u32* packed = (u32*)(ws + o_packed);

        k_prep_hist<<<NG * NS + 1 + XB_BLOCKS, 1024, 0, stream>>>(
            x, bases, loopw, dst, wfp, xb, priv);
        k_scan_block<<<SCAN_BLOCKS, 1024, 0, stream>>>(priv, counts, offs, bsums);
        k_scatter<<<NG * NS, 1024, 0, stream>>>(dst, src, et, priv, bsums,
                                                boffs, packed);
        k_agg<<<2048, 256, 0, stream>>>(xb, (const float4*)comp, packed,
                                        offs, boffs, counts, (uint2*)y);
        k_gemm_ln<<<(N_NODES / 16 + 3) / 4, 256, 0, stream>>>(
            (const short8*)y, (const short8*)xb, (const short8*)wfp,
            bias, gamma, beta, out);
    } else {
        hipMemsetAsync(d_out, 0, (size_t)N_NODES * 64 * sizeof(float), stream);
        k_edge_direct<<<(N_EDGES + 3) / 4, 256, 0, stream>>>(
            x, bases, comp, src, dst, et, out);
        k_finalize<<<2048, 256, 0, stream>>>(x, loopw, bias, gamma, beta, out);
    }
}